// Round 1
// baseline (524.055 us; speedup 1.0000x reference)
//
#include <hip/hip_runtime.h>

// Problem constants (fixed by the harness problem definition)
#define TT 2000
#define NN 64
#define CC 512
#define SS 200
#define LL 401          // 2*S+1 extended states
#define NEGV -1e30f
#define PF 6            // register prefetch depth (rows of log_probs in flight)

__global__ __launch_bounds__(512, 1)
void ctc_alpha(const float* __restrict__ lp,        // (T,N,C) log-probs
               const int*  __restrict__ targets,    // (N,S)
               const int*  __restrict__ in_len,     // (N)
               const int*  __restrict__ tgt_len,    // (N)
               float*      __restrict__ loss_ws)    // (N) per-batch loss/tl
{
    const int n   = blockIdx.x;
    const int tid = threadIdx.x;

    __shared__ float smrow[2][CC];     // double-buffered log-prob row
    __shared__ float alpha[2][LL];     // double-buffered alpha

    // Per-thread static state: extended label class + skip-transition allowed
    int  ext_c  = 0;        // blank for even s
    bool allow3 = false;
    if (tid < LL && (tid & 1)) {
        ext_c = targets[n * SS + (tid >> 1)];
        if (tid >= 3)
            allow3 = (ext_c != targets[n * SS + ((tid - 3) >> 1)]);
        // s==1: reference shifts NEG into a3 anyway -> allow3 stays false
    }

    const int inlen = in_len[n];
    const float* lpn = lp + (size_t)n * CC;         // (t=0, n, 0)
    const size_t rowstride = (size_t)NN * CC;

    // stage row t=0 (coalesced: 1 float/thread, block==CC)
    smrow[0][tid] = lpn[tid];

    // prefetch rows 1..PF into registers (static circular buffer)
    float rbuf[PF];
    const float* pf_ptr = lpn + rowstride;
    #pragma unroll
    for (int u = 0; u < PF; ++u) {
        rbuf[u] = pf_ptr[tid];
        pf_ptr += rowstride;
    }
    // pf_ptr now points at row 1+PF

    __syncthreads();

    // alpha_0: only s=0 (blank) and s=1 (first label) reachable
    if (tid < LL)
        alpha[0][tid] = (tid < 2) ? smrow[0][ext_c] : NEGV;

    int t = 1;
    while (t < TT) {
        #pragma unroll
        for (int u = 0; u < PF; ++u) {
            if (t < TT) {
                const int cb = t & 1, pb = cb ^ 1;
                // commit prefetched row t to LDS; issue load for row t+PF
                smrow[cb][tid] = rbuf[u];
                if (t + PF < TT) rbuf[u] = pf_ptr[tid];
                pf_ptr += rowstride;
                __syncthreads();   // row t visible + alpha[pb] complete
                if (tid < LL) {
                    float a1 = alpha[pb][tid];
                    float a2 = (tid >= 1) ? alpha[pb][tid - 1] : NEGV;
                    float a3 = allow3   ? alpha[pb][tid - 2] : NEGV;
                    float m  = fmaxf(a1, fmaxf(a2, a3));
                    float s  = __expf(a1 - m) + __expf(a2 - m) + __expf(a3 - m);
                    float nv = m + __logf(s) + smrow[cb][ext_c];
                    alpha[cb][tid] = (t < inlen) ? nv : a1;  // freeze past input_len
                }
                ++t;
            }
        }
    }

    __syncthreads();
    if (tid == 0) {
        const int tl = tgt_len[n];
        const int fb = (TT - 1) & 1;
        float a1 = alpha[fb][2 * tl - 1];
        float a2 = alpha[fb][2 * tl];
        float m  = fmaxf(a1, a2);
        float l  = -(m + __logf(__expf(a1 - m) + __expf(a2 - m)));
        loss_ws[n] = l / (float)tl;
    }
}

__global__ void ctc_reduce(const float* __restrict__ loss_ws, float* __restrict__ out)
{
    float v = loss_ws[threadIdx.x];   // 64 threads = 1 wave
    #pragma unroll
    for (int off = 32; off > 0; off >>= 1)
        v += __shfl_down(v, off);
    if (threadIdx.x == 0)
        out[0] = v / (float)NN;
}

extern "C" void kernel_launch(void* const* d_in, const int* in_sizes, int n_in,
                              void* d_out, int out_size, void* d_ws, size_t ws_size,
                              hipStream_t stream)
{
    const float* lp      = (const float*)d_in[0];
    const int*   targets = (const int*)d_in[1];
    const int*   in_len  = (const int*)d_in[2];
    const int*   tgt_len = (const int*)d_in[3];
    float*       out     = (float*)d_out;
    float*       ws      = (float*)d_ws;

    hipLaunchKernelGGL(ctc_alpha, dim3(NN), dim3(512), 0, stream,
                       lp, targets, in_len, tgt_len, ws);
    hipLaunchKernelGGL(ctc_reduce, dim3(1), dim3(64), 0, stream, ws, out);
}